// Round 5
// baseline (147.950 us; speedup 1.0000x reference)
//
#include <hip/hip_runtime.h>
#include <hip/hip_bf16.h>

#define NQH 64
#define NKVH 8
#define DH 64
#define SEQ 1024
#define HID 2880
#define QKV_N 5120   // (NQ+2*NKV)*DH
#define ATTN_N 4096  // NQ*DH
#define WIN 128
#define WO_NPAD 2944 // 23*128
#define SCALE_F 0.125f

typedef __attribute__((ext_vector_type(8))) __bf16 bf16x8;
typedef __attribute__((ext_vector_type(4))) float f32x4;

#define GLOAD_LDS16(g, l) \
    __builtin_amdgcn_global_load_lds((const __attribute__((address_space(1))) void*)(g), \
                                     (__attribute__((address_space(3))) void*)(l), 16, 0, 0)

__device__ __forceinline__ ushort f2bf(float x) {
    union { float f; unsigned int u; } c; c.f = x;
    unsigned int u = c.u;
    unsigned int r = (u + 0x7FFFu + ((u >> 16) & 1u)) >> 16;
    return (ushort)r;
}

// ---------------------------------------------------------------- convert (plain)
__global__ __launch_bounds__(256) void convert_f32_bf16(
    const float* __restrict__ in, ushort* __restrict__ out, int n4)
{
    int idx = blockIdx.x * blockDim.x + threadIdx.x;
    int stride = gridDim.x * blockDim.x;
    for (int i = idx; i < n4; i += stride) {
        float4 v = reinterpret_cast<const float4*>(in)[i];
        ushort4 o;
        o.x = f2bf(v.x); o.y = f2bf(v.y); o.z = f2bf(v.z); o.w = f2bf(v.w);
        reinterpret_cast<ushort4*>(out)[i] = o;
    }
}

// ---------------------------------------------------------------- transpose+convert
// in: [K][N] f32  ->  out: [Npad][K] bf16 (rows >= N zero-filled). K,Npad multiples of 64.
__global__ __launch_bounds__(256) void transpose_convert(
    const float* __restrict__ in, ushort* __restrict__ out, int K, int N)
{
    __shared__ ushort tile[64][80];   // row stride 160B (16B-aligned for uint4)
    const int bk = blockIdx.x * 64;   // k tile origin
    const int bn = blockIdx.y * 64;   // n tile origin
    const int tid = threadIdx.x;
    const bool inb = bn < N;          // whole tile valid or whole tile pad (N % 64 == 0)

#pragma unroll
    for (int it = 0; it < 4; ++it) {
        int r = it * 16 + (tid >> 4);         // k offset 0..63
        int c4 = (tid & 15) * 4;              // n offset
        float4 v = make_float4(0.f, 0.f, 0.f, 0.f);
        if (inb) v = *(const float4*)&in[(size_t)(bk + r) * N + bn + c4];
        tile[c4 + 0][r] = f2bf(v.x);
        tile[c4 + 1][r] = f2bf(v.y);
        tile[c4 + 2][r] = f2bf(v.z);
        tile[c4 + 3][r] = f2bf(v.w);
    }
    __syncthreads();
#pragma unroll
    for (int it = 0; it < 2; ++it) {
        int nr = it * 32 + (tid >> 3);        // n offset 0..63
        int c8 = (tid & 7) * 8;               // k offset
        uint4 v = *(const uint4*)&tile[nr][c8];
        *(uint4*)&out[(size_t)(bn + nr) * K + bk + c8] = v;
    }
}

// ---------------------------------------------------------------- GEMM 64x128, BK=64, 2-phase dbuf
// A: [M][K] bf16, BT: [Npad][K] bf16, C: [M][ldC] f32 (+bias), K % 64 == 0, K/64 >= 2.
// 256 threads = 4 waves, wave tile 32x64. Double-buffered LDS; tile t+1's global_load_lds
// issued BEFORE compute(t) so the end-of-iter barrier's vmcnt(0) drain lands after
// ~224cyc of ds_read+MFMA (T3 2-phase minimum). One barrier per K-step.
template<bool ROPE>
__global__ __launch_bounds__(256) void gemm64x128(
    const ushort* __restrict__ A, const ushort* __restrict__ BT,
    const float* __restrict__ bias, float* __restrict__ C,
    int K, int ldC, int Nreal,
    const float* __restrict__ cosp, const float* __restrict__ sinp)
{
    __shared__ ushort Al[2 * 64 * 64];    // 2 x 8 KB
    __shared__ ushort Bl[2 * 128 * 64];   // 2 x 16 KB
    const int t = threadIdx.x;
    const int lane = t & 63;
    const int w = t >> 6;
    const int wr = w >> 1, wc = w & 1;
    const int g4 = lane >> 4;
    const int r15 = lane & 15;

    // bijective XCD swizzle (nwg % 8 == 0)
    const int flat = blockIdx.x + gridDim.x * blockIdx.y;
    const int per = (gridDim.x * gridDim.y) >> 3;
    const int virt = (flat & 7) * per + (flat >> 3);
    const int m0 = (virt & 15) * 64;
    const int n0 = (virt >> 4) * 128;

    // ---- staging pointers (inverse-swizzled global source, linear LDS dest)
    const ushort* aSrc0; const ushort* aSrc1;
    ushort* aDst0; ushort* aDst1;
    {
        int lin0 = t, lin1 = 256 + t;
        int row0 = lin0 >> 3, row1 = lin1 >> 3;
        int ch0 = (lin0 & 7) ^ (row0 & 7);
        int ch1 = (lin1 & 7) ^ (row1 & 7);
        aSrc0 = A + (size_t)(m0 + row0) * K + ch0 * 8;
        aSrc1 = A + (size_t)(m0 + row1) * K + ch1 * 8;
        aDst0 = &Al[lin0 * 8];
        aDst1 = &Al[lin1 * 8];
    }
    const ushort* bSrc0; const ushort* bSrc1; const ushort* bSrc2; const ushort* bSrc3;
    ushort* bDst0; ushort* bDst1; ushort* bDst2; ushort* bDst3;
    {
        int lin;
        lin = t;       bSrc0 = BT + (size_t)(n0 + (lin >> 3)) * K + (((lin & 7) ^ ((lin >> 3) & 7)) * 8); bDst0 = &Bl[lin * 8];
        lin = 256 + t; bSrc1 = BT + (size_t)(n0 + (lin >> 3)) * K + (((lin & 7) ^ ((lin >> 3) & 7)) * 8); bDst1 = &Bl[lin * 8];
        lin = 512 + t; bSrc2 = BT + (size_t)(n0 + (lin >> 3)) * K + (((lin & 7) ^ ((lin >> 3) & 7)) * 8); bDst2 = &Bl[lin * 8];
        lin = 768 + t; bSrc3 = BT + (size_t)(n0 + (lin >> 3)) * K + (((lin & 7) ^ ((lin >> 3) & 7)) * 8); bDst3 = &Bl[lin * 8];
    }

#define STAGE_TILE(bufsel) do { \
        GLOAD_LDS16(aSrc0, aDst0 + (bufsel) * 4096); \
        GLOAD_LDS16(aSrc1, aDst1 + (bufsel) * 4096); \
        GLOAD_LDS16(bSrc0, bDst0 + (bufsel) * 8192); \
        GLOAD_LDS16(bSrc1, bDst1 + (bufsel) * 8192); \
        GLOAD_LDS16(bSrc2, bDst2 + (bufsel) * 8192); \
        GLOAD_LDS16(bSrc3, bDst3 + (bufsel) * 8192); \
        aSrc0 += 64; aSrc1 += 64; \
        bSrc0 += 64; bSrc1 += 64; bSrc2 += 64; bSrc3 += 64; \
    } while (0)

    // ---- fragment read offsets (element units), swizzled
    int aoff[2][2], boff[4][2];
#pragma unroll
    for (int mi = 0; mi < 2; ++mi)
#pragma unroll
        for (int ks = 0; ks < 2; ++ks) {
            int row = wr * 32 + mi * 16 + r15;
            int slot = (ks * 4 + g4) ^ (row & 7);
            aoff[mi][ks] = row * 64 + slot * 8;
        }
#pragma unroll
    for (int ni = 0; ni < 4; ++ni)
#pragma unroll
        for (int ks = 0; ks < 2; ++ks) {
            int col = wc * 64 + ni * 16 + r15;
            int slot = (ks * 4 + g4) ^ (col & 7);
            boff[ni][ks] = col * 64 + slot * 8;
        }

    f32x4 acc[2][4];
#pragma unroll
    for (int mi = 0; mi < 2; ++mi)
#pragma unroll
        for (int ni = 0; ni < 4; ++ni) acc[mi][ni] = (f32x4){0.f, 0.f, 0.f, 0.f};

#define COMPUTE_TILE(bufsel) do { \
        const ushort* Ab = &Al[(bufsel) * 4096]; \
        const ushort* Bb = &Bl[(bufsel) * 8192]; \
        _Pragma("unroll") \
        for (int ks = 0; ks < 2; ++ks) { \
            bf16x8 a0 = *(const bf16x8*)&Ab[aoff[0][ks]]; \
            bf16x8 a1 = *(const bf16x8*)&Ab[aoff[1][ks]]; \
            bf16x8 b0 = *(const bf16x8*)&Bb[boff[0][ks]]; \
            bf16x8 b1 = *(const bf16x8*)&Bb[boff[1][ks]]; \
            bf16x8 b2 = *(const bf16x8*)&Bb[boff[2][ks]]; \
            bf16x8 b3 = *(const bf16x8*)&Bb[boff[3][ks]]; \
            acc[0][0] = __builtin_amdgcn_mfma_f32_16x16x32_bf16(a0, b0, acc[0][0], 0, 0, 0); \
            acc[0][1] = __builtin_amdgcn_mfma_f32_16x16x32_bf16(a0, b1, acc[0][1], 0, 0, 0); \
            acc[0][2] = __builtin_amdgcn_mfma_f32_16x16x32_bf16(a0, b2, acc[0][2], 0, 0, 0); \
            acc[0][3] = __builtin_amdgcn_mfma_f32_16x16x32_bf16(a0, b3, acc[0][3], 0, 0, 0); \
            acc[1][0] = __builtin_amdgcn_mfma_f32_16x16x32_bf16(a1, b0, acc[1][0], 0, 0, 0); \
            acc[1][1] = __builtin_amdgcn_mfma_f32_16x16x32_bf16(a1, b1, acc[1][1], 0, 0, 0); \
            acc[1][2] = __builtin_amdgcn_mfma_f32_16x16x32_bf16(a1, b2, acc[1][2], 0, 0, 0); \
            acc[1][3] = __builtin_amdgcn_mfma_f32_16x16x32_bf16(a1, b3, acc[1][3], 0, 0, 0); \
        } \
    } while (0)

    const int NT = K >> 6;
    // prologue: tile 0 -> buf 0
    STAGE_TILE(0);
    __syncthreads();                       // vmcnt(0) drain: tile 0 ready
    for (int kt = 0; kt < NT; kt += 2) {
        if (kt + 1 < NT) STAGE_TILE(1);    // prefetch next BEFORE compute
        COMPUTE_TILE(0);
        __syncthreads();                   // drain prefetch + ds_reads, release buf0
        if (kt + 1 < NT) {
            if (kt + 2 < NT) STAGE_TILE(0);
            COMPUTE_TILE(1);
            __syncthreads();
        }
    }
#undef STAGE_TILE
#undef COMPUTE_TILE

    // ---- epilogue: bias (+ optional fused RoPE), f32 store
    // D frag: row = (lane>>4)*4 + r (+16*mi +32*wr +m0), col = lane&15 (+16*ni +64*wc +n0)
    float vals[2][4][4];
#pragma unroll
    for (int ni = 0; ni < 4; ++ni) {
        int col = n0 + wc * 64 + ni * 16 + r15;
        float bv = (col < Nreal) ? bias[col] : 0.f;
#pragma unroll
        for (int mi = 0; mi < 2; ++mi)
#pragma unroll
            for (int r = 0; r < 4; ++r) vals[mi][ni][r] = acc[mi][ni][r] + bv;
    }
    if (ROPE) {
        const int head = (n0 + wc * 64) >> 6;   // wave-half = exactly one 64-col head
        if (head < 72) {                         // q heads 0..63, k heads 64..71; v passthrough
#pragma unroll
            for (int mi = 0; mi < 2; ++mi)
#pragma unroll
                for (int r = 0; r < 4; ++r) {
                    int q = m0 + wr * 32 + mi * 16 + g4 * 4 + r;
#pragma unroll
                    for (int dp = 0; dp < 2; ++dp) {
                        int d = dp * 16 + r15;
                        float c = cosp[q * 32 + d];
                        float s = sinp[q * 32 + d];
                        float x1 = vals[mi][dp][r];
                        float x2 = vals[mi][dp + 2][r];
                        vals[mi][dp][r]     = x1 * c - x2 * s;
                        vals[mi][dp + 2][r] = x2 * c + x1 * s;
                    }
                }
        }
    }
#pragma unroll
    for (int ni = 0; ni < 4; ++ni) {
        int col = n0 + wc * 64 + ni * 16 + r15;
        if (col < Nreal) {
#pragma unroll
            for (int mi = 0; mi < 2; ++mi) {
                int row = m0 + wr * 32 + mi * 16 + g4 * 4;
#pragma unroll
                for (int r = 0; r < 4; ++r)
                    C[(size_t)(row + r) * ldC + col] = vals[mi][ni][r];
            }
        }
    }
}

// ---------------------------------------------------------------- MFMA flash attention
__global__ __launch_bounds__(512) void attn_mfma_kernel(
    const float* __restrict__ qkv, const float* __restrict__ sinks,
    ushort* __restrict__ attn_out)
{
    __shared__ __align__(16) ushort Kl[160][72];    // [key][d], pad 64->72 (2-way free)
    __shared__ __align__(16) ushort Vt[64][168];    // [d][key], pad 160->168 (2-way free)
    __shared__ __align__(16) ushort Pl[8][32][40];  // per-wave P chunk [row][32 keys], pad->40
    const int t = threadIdx.x;
    const int w = t >> 6;
    const int l = t & 63;
    const int g4 = l >> 4;
    const int r15 = l & 15;
    const int q0 = blockIdx.x * 32;
    const int hk = blockIdx.y;
    const int kbase = q0 - 128;

    // ---- stage K [160][64] f32->bf16 and V^T [64][160]
#pragma unroll
    for (int i = 0; i < 5; ++i) {
        int idx = i * 512 + t;             // 0..2559
        int row = idx >> 4;                // 0..159
        int c4 = (idx & 15) * 4;           // 0..60
        int j = kbase + row;
        float4 kv = make_float4(0.f, 0.f, 0.f, 0.f);
        float4 vv = make_float4(0.f, 0.f, 0.f, 0.f);
        if (j >= 0) {
            kv = *(const float4*)&qkv[(size_t)j * QKV_N + 4096 + hk * 64 + c4];
            vv = *(const float4*)&qkv[(size_t)j * QKV_N + 4608 + hk * 64 + c4];
        }
        ushort4 kp;
        kp.x = f2bf(kv.x); kp.y = f2bf(kv.y); kp.z = f2bf(kv.z); kp.w = f2bf(kv.w);
        *(ushort4*)&Kl[row][c4] = kp;
        Vt[c4 + 0][row] = f2bf(vv.x);
        Vt[c4 + 1][row] = f2bf(vv.y);
        Vt[c4 + 2][row] = f2bf(vv.z);
        Vt[c4 + 3][row] = f2bf(vv.w);
    }

    // ---- Q fragments (B operand: lane supplies col = score-row = r15+16ct, k = d)
    bf16x8 qf[2][2];
#pragma unroll
    for (int ct = 0; ct < 2; ++ct) {
        int R = w * 32 + ct * 16 + r15;
        int q = q0 + (R & 31);
        int hq = hk * 8 + (R >> 5);
        const float* qb = &qkv[(size_t)q * QKV_N + hq * 64];
#pragma unroll
        for (int s = 0; s < 2; ++s) {
            float4 a = *(const float4*)&qb[s * 32 + g4 * 8];
            float4 b = *(const float4*)&qb[s * 32 + g4 * 8 + 4];
            union { ushort u[8]; bf16x8 v; } pk;
            pk.u[0] = f2bf(a.x * SCALE_F); pk.u[1] = f2bf(a.y * SCALE_F);
            pk.u[2] = f2bf(a.z * SCALE_F); pk.u[3] = f2bf(a.w * SCALE_F);
            pk.u[4] = f2bf(b.x * SCALE_F); pk.u[5] = f2bf(b.y * SCALE_F);
            pk.u[6] = f2bf(b.z * SCALE_F); pk.u[7] = f2bf(b.w * SCALE_F);
            qf[ct][s] = pk.v;
        }
    }
    __syncthreads();

    // ---- S^T = K @ Q^T : D row = key = 16kt+4g4+r, col = score-row = 16ct+r15 (+32w)
    f32x4 sc[10][2];
#pragma unroll
    for (int kt = 0; kt < 10; ++kt) {
        sc[kt][0] = (f32x4){0.f, 0.f, 0.f, 0.f};
        sc[kt][1] = (f32x4){0.f, 0.f, 0.f, 0.f};
    }
#pragma unroll
    for (int kt = 0; kt < 10; ++kt) {
#pragma unroll
        for (int s = 0; s < 2; ++s) {
            bf16x8 kf = *(const bf16x8*)&Kl[kt * 16 + r15][s * 32 + g4 * 8];
            sc[kt][0] = __builtin_amdgcn_mfma_f32_16x16x32_bf16(kf, qf[0][s], sc[kt][0], 0, 0, 0);
            sc[kt][1] = __builtin_amdgcn_mfma_f32_16x16x32_bf16(kf, qf[1][s], sc[kt][1], 0, 0, 0);
        }
    }

    // ---- masked softmax, per score-row; fold sink and 1/denom (all lane-local)
    const int minkey = 128 - q0;          // key_local >= minkey  <=>  j >= 0
#pragma unroll
    for (int ct = 0; ct < 2; ++ct) {
        int R = w * 32 + ct * 16 + r15;
        int ql = R & 31;
        float snk = sinks[hk * 8 + (R >> 5)];
#pragma unroll
        for (int kt = 0; kt < 10; ++kt)
#pragma unroll
            for (int r = 0; r < 4; ++r) {
                int key = kt * 16 + g4 * 4 + r;
                // allowed: q_local < key <= q_local+128 (window+causal), key >= minkey (j>=0)
                bool ok = (key > ql) && (key <= ql + 128) && (key >= minkey);
                if (!ok) sc[kt][ct][r] = -1e30f;
            }
        float m = snk;
#pragma unroll
        for (int kt = 0; kt < 10; ++kt)
#pragma unroll
            for (int r = 0; r < 4; ++r) m = fmaxf(m, sc[kt][ct][r]);
        m = fmaxf(m, __shfl_xor(m, 16));
        m = fmaxf(m, __shfl_xor(m, 32));
        float sum = 0.f;
#pragma unroll
        for (int kt = 0; kt < 10; ++kt)
#pragma unroll
            for (int r = 0; r < 4; ++r) {
                float p = __expf(sc[kt][ct][r] - m);
                sc[kt][ct][r] = p;
                sum += p;
            }
        sum += __shfl_xor(sum, 16);
        sum += __shfl_xor(sum, 32);
        sum += __expf(snk - m);
        float iv = 1.0f / sum;
#pragma unroll
        for (int kt = 0; kt < 10; ++kt)
#pragma unroll
            for (int r = 0; r < 4; ++r) sc[kt][ct][r] *= iv;
    }

    // ---- PV: out[row][d] = sum_key P[row][key] * V[key][d]
    f32x4 pv[2][4];
#pragma unroll
    for (int mi = 0; mi < 2; ++mi)
#pragma unroll
        for (int ni = 0; ni < 4; ++ni) pv[mi][ni] = (f32x4){0.f, 0.f, 0.f, 0.f};

#pragma unroll
    for (int s = 0; s < 5; ++s) {
#pragma unroll
        for (int ct = 0; ct < 2; ++ct)
#pragma unroll
            for (int kh = 0; kh < 2; ++kh) {
                int kt = 2 * s + kh;
                ushort4 p4;
                p4.x = f2bf(sc[kt][ct][0]);
                p4.y = f2bf(sc[kt][ct][1]);
                p4.z = f2bf(sc[kt][ct][2]);
                p4.w = f2bf(sc[kt][ct][3]);
                *(ushort4*)&Pl[w][ct * 16 + r15][kh * 16 + g4 * 4] = p4;
            }
#pragma unroll
        for (int mi = 0; mi < 2; ++mi) {
            bf16x8 pf = *(const bf16x8*)&Pl[w][mi * 16 + r15][g4 * 8];
#pragma unroll
            for (int ni = 0; ni < 4; ++ni) {
                bf16x8 vf = *(const bf16x8*)&Vt[ni * 16 + r15][s * 32 + g4 * 8];
                pv[mi][ni] = __builtin_amdgcn_mfma_f32_16x16x32_bf16(pf, vf, pv[mi][ni], 0, 0, 0);
            }
        }
    }

    // ---- write attn output (bf16): D row = 16mi+4g4+r (+32w), col = d = 16ni+r15
#pragma unroll
    for (int mi = 0; mi < 2; ++mi)
#pragma unroll
        for (int r = 0; r < 4; ++r) {
            int R = w * 32 + mi * 16 + g4 * 4 + r;
            int q = q0 + (R & 31);
            int hq = hk * 8 + (R >> 5);
            ushort* ob = &attn_out[(size_t)q * ATTN_N + hq * 64 + r15];
#pragma unroll
            for (int ni = 0; ni < 4; ++ni)
                ob[ni * 16] = f2bf(pv[mi][ni][r]);
        }
}

// ---------------------------------------------------------------- launch
extern "C" void kernel_launch(void* const* d_in, const int* in_sizes, int n_in,
                              void* d_out, int out_size, void* d_ws, size_t ws_size,
                              hipStream_t stream)
{
    const float* hidden = (const float*)d_in[0];
    const float* cosp   = (const float*)d_in[1];
    const float* sinp   = (const float*)d_in[2];
    const float* w_qkv  = (const float*)d_in[3];
    const float* b_qkv  = (const float*)d_in[4];
    const float* w_o    = (const float*)d_in[5];
    const float* b_o    = (const float*)d_in[6];
    const float* sinks  = (const float*)d_in[7];
    // d_in[8]=k_cache, d_in[9]=v_cache (zero), d_in[10]=kv_len (==0): unused.

    char* ws = (char*)d_ws;
    size_t off = 0;
    ushort* wqkvT = (ushort*)(ws + off); off += (size_t)QKV_N * HID * 2;      // [5120][2880]
    ushort* woT   = (ushort*)(ws + off); off += (size_t)WO_NPAD * ATTN_N * 2; // [2944][4096]
    float*  qkv   = (float*)(ws + off);  off += (size_t)SEQ * QKV_N * 4;
    // union region: hidden_b (gemm1 A) then attn_b (gemm2 A) — lifetimes disjoint
    ushort* hidden_b = (ushort*)(ws + off);
    ushort* attn_b   = (ushort*)(ws + off); off += (size_t)SEQ * ATTN_N * 2;
    if (off > ws_size) return;  // fail visibly rather than corrupt

    // weight transposes + hidden convert
    transpose_convert<<<dim3(HID / 64, QKV_N / 64), 256, 0, stream>>>(w_qkv, wqkvT, HID, QKV_N);
    transpose_convert<<<dim3(ATTN_N / 64, WO_NPAD / 64), 256, 0, stream>>>(w_o, woT, ATTN_N, HID);
    convert_f32_bf16<<<2048, 256, 0, stream>>>(hidden, hidden_b, SEQ * HID / 4);

    // QKV projection with fused RoPE epilogue
    gemm64x128<true><<<dim3(QKV_N / 128, SEQ / 64), 256, 0, stream>>>(
        hidden_b, wqkvT, b_qkv, qkv, HID, QKV_N, QKV_N, cosp, sinp);

    // MFMA flash attention: grid (q-tiles, kv-heads)
    attn_mfma_kernel<<<dim3(SEQ / 32, NKVH), 512, 0, stream>>>(qkv, sinks, attn_b);

    // output projection
    gemm64x128<false><<<dim3(WO_NPAD / 128, SEQ / 64), 256, 0, stream>>>(
        attn_b, woT, b_o, (float*)d_out, ATTN_N, HID, HID, nullptr, nullptr);
}